// Round 7
// baseline (120.681 us; speedup 1.0000x reference)
//
#include <hip/hip_runtime.h>

// B=16, N=128, F_IN=8, FC=256, H=256, E=N*(N-1)=16256, rows=B*E=260096, TAU=0.5
//
// Collapse (exact): graph is broadcast from graph[0,0] -> identical rows ->
// batchnorm over identical rows outputs exactly beta for both MLPs. Head input
// is one 512-vector [m2_beta, m2_beta] for ALL B*E rows: logits L[8] and
// prob=softmax(L) are computed ONCE; per-row work is only
// g_graph = softmax((L + gumbel)/TAU).
//
// Round-7: single fused kernel (1 graph node). Blocks 0..63 compute the head
// chain with inter-block flag barriers (agent-scope atomics, magic-value
// flags that are poison-tolerant and replay-safe: stale-set flags only ever
// expose bit-identical data from the previous deterministic replay). All 512
// blocks then do the gumbel rows; iteration-0 loads are issued BEFORE the
// DONE-wait so the bulk read overlaps the head chain.

#define FC   256
#define HID  256
#define NOUT 8

#define GRID 512
#define TPB  256
#define MAGIC 0x5AC0DE01

// ws float offsets
#define WS_L    0
#define WS_PROB 8
#define WS_H    64
#define WS_O1   320
#define WS_O2   576
// ws int offsets (bytes 4096+)
#define WF1   1024
#define WF2   1088
#define WF3   1152
#define WDONE 1216

__device__ __forceinline__ void stf(float* p, float v) {
    __hip_atomic_store(p, v, __ATOMIC_RELAXED, __HIP_MEMORY_SCOPE_AGENT);
}
__device__ __forceinline__ float ldf(float* p) {
    return __hip_atomic_load(p, __ATOMIC_RELAXED, __HIP_MEMORY_SCOPE_AGENT);
}
__device__ __forceinline__ void set_flag(int* p) {
    __hip_atomic_store(p, MAGIC, __ATOMIC_RELEASE, __HIP_MEMORY_SCOPE_AGENT);
}
__device__ __forceinline__ void wait_flag(int* p) {
    while (__hip_atomic_load(p, __ATOMIC_ACQUIRE, __HIP_MEMORY_SCOPE_AGENT) != MAGIC)
        __builtin_amdgcn_s_sleep(1);
}

__global__ __launch_bounds__(TPB, 2) void fused_kernel(
    const float* __restrict__ gn,
    const float* __restrict__ beta,
    const float* __restrict__ Wi, const float* __restrict__ bi,
    const float* __restrict__ Wn, const float* __restrict__ bn_b,
    const float* __restrict__ f1W, const float* __restrict__ f1b,
    const float* __restrict__ f2W, const float* __restrict__ f2b,
    const float* __restrict__ f3W, const float* __restrict__ f3b,
    float* __restrict__ out, float* __restrict__ wsf, int rows)
{
    const int bid = blockIdx.x;
    const int t   = threadIdx.x;
    int* wsi = reinterpret_cast<int*>(wsf);

    // ---- prefetch iteration-0 gumbel row (overlaps the head chain) ----------
    const int r0 = bid * TPB + t;
    float4 ga = make_float4(0.f, 0.f, 0.f, 0.f), gb = ga;
    if (r0 < rows) {
        const float4* gp = reinterpret_cast<const float4*>(gn + (size_t)r0 * NOUT);
        ga = gp[0]; gb = gp[1];
    }

    __shared__ float lds8[4][8];
    __shared__ float red[NOUT * 256];
    __shared__ float sLp[16];

    if (bid < 64) {
        const int c0 = bid * 4;
        const int lane = t & 63, wid = t >> 6;

        // ---------- phase 1: gate  h = (1-sigmoid(c@Wi+bi))*tanh(c@Wn+bn) ----
        {
            const float ck = beta[t];
            const float4 wi0 = *reinterpret_cast<const float4*>(&Wi[(size_t)t * HID + c0]);
            const float4 wi1 = *reinterpret_cast<const float4*>(&Wi[(size_t)(t + 256) * HID + c0]);
            const float4 wn0 = *reinterpret_cast<const float4*>(&Wn[(size_t)t * HID + c0]);
            const float4 wn1 = *reinterpret_cast<const float4*>(&Wn[(size_t)(t + 256) * HID + c0]);
            float v[8];
            v[0]=ck*(wi0.x+wi1.x); v[1]=ck*(wi0.y+wi1.y); v[2]=ck*(wi0.z+wi1.z); v[3]=ck*(wi0.w+wi1.w);
            v[4]=ck*(wn0.x+wn1.x); v[5]=ck*(wn0.y+wn1.y); v[6]=ck*(wn0.z+wn1.z); v[7]=ck*(wn0.w+wn1.w);
            #pragma unroll
            for (int off = 32; off; off >>= 1) {
                #pragma unroll
                for (int j = 0; j < 8; ++j) v[j] += __shfl_xor(v[j], off, 64);
            }
            if (lane == 0) {
                #pragma unroll
                for (int j = 0; j < 8; ++j) lds8[wid][j] = v[j];
            }
            __syncthreads();
            if (t < 4) {
                const float ai = lds8[0][t]+lds8[1][t]+lds8[2][t]+lds8[3][t];
                const float an = lds8[0][4+t]+lds8[1][4+t]+lds8[2][4+t]+lds8[3][4+t];
                const int c = c0 + t;
                const float iv = 1.f / (1.f + expf(-(ai + bi[c])));
                const float nv = tanhf(an + bn_b[c]);
                stf(&wsf[WS_H + c], (1.f - iv) * nv);
            }
            __syncthreads();
            if (t == 0) set_flag(&wsi[WF1 + bid]);
        }

        // ---------- phase 2: o1 = relu(h @ f1W + f1b) -------------------------
        wait_flag(&wsi[WF1 + (t & 63)]);
        __syncthreads();
        {
            const float hv = ldf(&wsf[WS_H + t]);
            const float4 w = *reinterpret_cast<const float4*>(&f1W[(size_t)t * HID + c0]);
            float v[4] = {hv*w.x, hv*w.y, hv*w.z, hv*w.w};
            #pragma unroll
            for (int off = 32; off; off >>= 1) {
                #pragma unroll
                for (int j = 0; j < 4; ++j) v[j] += __shfl_xor(v[j], off, 64);
            }
            if (lane == 0) {
                #pragma unroll
                for (int j = 0; j < 4; ++j) lds8[wid][j] = v[j];
            }
            __syncthreads();
            if (t < 4) {
                const float a = lds8[0][t]+lds8[1][t]+lds8[2][t]+lds8[3][t];
                stf(&wsf[WS_O1 + c0 + t], fmaxf(a + f1b[c0 + t], 0.f));
            }
            __syncthreads();
            if (t == 0) set_flag(&wsi[WF2 + bid]);
        }

        // ---------- phase 3: o2 = relu(o1 @ f2W + f2b) ------------------------
        wait_flag(&wsi[WF2 + (t & 63)]);
        __syncthreads();
        {
            const float hv = ldf(&wsf[WS_O1 + t]);
            const float4 w = *reinterpret_cast<const float4*>(&f2W[(size_t)t * HID + c0]);
            float v[4] = {hv*w.x, hv*w.y, hv*w.z, hv*w.w};
            #pragma unroll
            for (int off = 32; off; off >>= 1) {
                #pragma unroll
                for (int j = 0; j < 4; ++j) v[j] += __shfl_xor(v[j], off, 64);
            }
            if (lane == 0) {
                #pragma unroll
                for (int j = 0; j < 4; ++j) lds8[wid][j] = v[j];
            }
            __syncthreads();
            if (t < 4) {
                const float a = lds8[0][t]+lds8[1][t]+lds8[2][t]+lds8[3][t];
                stf(&wsf[WS_O2 + c0 + t], fmaxf(a + f2b[c0 + t], 0.f));
            }
            __syncthreads();
            if (t == 0) set_flag(&wsi[WF3 + bid]);
        }

        // ---------- phase 4: L = o2 @ f3W + f3b; prob = softmax(L) (block 0) --
        if (bid == 0) {
            wait_flag(&wsi[WF3 + (t & 63)]);
            __syncthreads();
            const float o2 = ldf(&wsf[WS_O2 + t]);
            const float4 wlo = *reinterpret_cast<const float4*>(&f3W[(size_t)t * NOUT]);
            const float4 whi = *reinterpret_cast<const float4*>(&f3W[(size_t)t * NOUT + 4]);
            red[0*256+t]=o2*wlo.x; red[1*256+t]=o2*wlo.y;
            red[2*256+t]=o2*wlo.z; red[3*256+t]=o2*wlo.w;
            red[4*256+t]=o2*whi.x; red[5*256+t]=o2*whi.y;
            red[6*256+t]=o2*whi.z; red[7*256+t]=o2*whi.w;
            __syncthreads();
            for (int s = 128; s; s >>= 1) {
                if (t < s) {
                    #pragma unroll
                    for (int j = 0; j < NOUT; ++j) red[j*256+t] += red[j*256+t+s];
                }
                __syncthreads();
            }
            if (t == 0) {
                float L[NOUT];
                #pragma unroll
                for (int j = 0; j < NOUT; ++j) L[j] = red[j*256] + f3b[j];
                float m = L[0];
                #pragma unroll
                for (int j = 1; j < NOUT; ++j) m = fmaxf(m, L[j]);
                float e[NOUT], s = 0.f;
                #pragma unroll
                for (int j = 0; j < NOUT; ++j) { e[j] = expf(L[j] - m); s += e[j]; }
                const float inv = 1.f / s;
                #pragma unroll
                for (int j = 0; j < NOUT; ++j) {
                    stf(&wsf[WS_L + j], L[j]);
                    stf(&wsf[WS_PROB + j], e[j] * inv);
                }
                set_flag(&wsi[WDONE]);
            }
        }
    }

    // ---------- gumbel: all 512 blocks, grid-stride over rows -----------------
    if (t == 0) wait_flag(&wsi[WDONE]);
    __syncthreads();
    if (t < 16) sLp[t] = ldf(&wsf[t]);   // L[0..7], prob[0..7]
    __syncthreads();

    float L2[NOUT];
    #pragma unroll
    for (int j = 0; j < NOUT; ++j) L2[j] = 2.f * sLp[j];   // 1/TAU = 2
    const float4 pr0 = make_float4(sLp[8],  sLp[9],  sLp[10], sLp[11]);
    const float4 pr1 = make_float4(sLp[12], sLp[13], sLp[14], sLp[15]);

    // iteration 0 (prefetched)
    if (r0 < rows) {
        float z[NOUT] = {ga.x, ga.y, ga.z, ga.w, gb.x, gb.y, gb.z, gb.w};
        float m = -1e30f;
        #pragma unroll
        for (int j = 0; j < NOUT; ++j) { z[j] = L2[j] + 2.f * z[j]; m = fmaxf(m, z[j]); }
        float s = 0.f;
        #pragma unroll
        for (int j = 0; j < NOUT; ++j) { z[j] = expf(z[j] - m); s += z[j]; }
        const float inv = 1.f / s;
        float4* op = reinterpret_cast<float4*>(out + (size_t)r0 * NOUT);
        op[0] = make_float4(z[0]*inv, z[1]*inv, z[2]*inv, z[3]*inv);
        op[1] = make_float4(z[4]*inv, z[5]*inv, z[6]*inv, z[7]*inv);
        float4* pp = reinterpret_cast<float4*>(out + (size_t)(rows + r0) * NOUT);
        pp[0] = pr0; pp[1] = pr1;
    }
    // iteration 1
    const int r1 = r0 + GRID * TPB;
    if (r1 < rows) {
        const float4* gp = reinterpret_cast<const float4*>(gn + (size_t)r1 * NOUT);
        const float4 h0 = gp[0];
        const float4 h1 = gp[1];
        float z[NOUT] = {h0.x, h0.y, h0.z, h0.w, h1.x, h1.y, h1.z, h1.w};
        float m = -1e30f;
        #pragma unroll
        for (int j = 0; j < NOUT; ++j) { z[j] = L2[j] + 2.f * z[j]; m = fmaxf(m, z[j]); }
        float s = 0.f;
        #pragma unroll
        for (int j = 0; j < NOUT; ++j) { z[j] = expf(z[j] - m); s += z[j]; }
        const float inv = 1.f / s;
        float4* op = reinterpret_cast<float4*>(out + (size_t)r1 * NOUT);
        op[0] = make_float4(z[0]*inv, z[1]*inv, z[2]*inv, z[3]*inv);
        op[1] = make_float4(z[4]*inv, z[5]*inv, z[6]*inv, z[7]*inv);
        float4* pp = reinterpret_cast<float4*>(out + (size_t)(rows + r1) * NOUT);
        pp[0] = pr0; pp[1] = pr1;
    }
}

extern "C" void kernel_launch(void* const* d_in, const int* in_sizes, int n_in,
                              void* d_out, int out_size, void* d_ws, size_t ws_size,
                              hipStream_t stream) {
    // 0 graph, 1 rel_rec, 2 rel_send, 3 gumbel_noise,
    // 4 m1_W1, 5 m1_b1, 6 m1_W2, 7 m1_b2, 8 m1_g, 9 m1_beta,
    // 10 m2_W1, 11 m2_b1, 12 m2_W2, 13 m2_b2, 14 m2_g, 15 m2_beta,
    // 16 Wi, 17 bi, 18 Wn, 19 bn_b, 20 f1_W, 21 f1_b, 22 f2_W, 23 f2_b,
    // 24 f3_W, 25 f3_b
    const float* gumbel  = (const float*)d_in[3];
    const float* m2_beta = (const float*)d_in[15];
    const float* Wi      = (const float*)d_in[16];
    const float* bi      = (const float*)d_in[17];
    const float* Wn      = (const float*)d_in[18];
    const float* bn_b    = (const float*)d_in[19];
    const float* f1W     = (const float*)d_in[20];
    const float* f1b     = (const float*)d_in[21];
    const float* f2W     = (const float*)d_in[22];
    const float* f2b     = (const float*)d_in[23];
    const float* f3W     = (const float*)d_in[24];
    const float* f3b     = (const float*)d_in[25];

    const int rows = in_sizes[3] / NOUT;   // 260096

    fused_kernel<<<GRID, TPB, 0, stream>>>(
        gumbel, m2_beta, Wi, bi, Wn, bn_b, f1W, f1b, f2W, f2b, f3W, f3b,
        (float*)d_out, (float*)d_ws, rows);
}

// Round 8
// 75.599 us; speedup vs baseline: 1.5963x; 1.5963x over previous
//
#include <hip/hip_runtime.h>
#include <hip/hip_cooperative_groups.h>

namespace cg = cooperative_groups;

// B=16, N=128, F_IN=8, FC=256, H=256, E=N*(N-1)=16256, rows=B*E=260096, TAU=0.5
//
// Collapse (exact): graph is broadcast from graph[0,0] -> identical rows ->
// batchnorm over identical rows outputs exactly beta for both MLPs. Head input
// is one 512-vector [m2_beta, m2_beta] for ALL B*E rows: logits L[8] and
// prob=softmax(L) are computed ONCE; per-row work is only
// g_graph = softmax((L + gumbel)/TAU).
//
// Round-8: R7 post-mortem showed per-lane agent-scope acquire/release ops
// cause L2 maintenance storms on gfx950 (150us at 70GB/s). Revert to R6 data
// plan; fuse the 4 head dispatches into ONE cooperative kernel (64 blocks,
// 3 grid.sync()) -> 2 graph nodes total. Gumbel kernel has zero device-scope
// ops and streams clean.

#define FC   256
#define HID  256
#define NOUT 8

// ws float offsets: [0..7]=L, [8..15]=prob, [64..319]=h, [320..575]=o1,
// [576..831]=o2
#define WS_H  64
#define WS_O1 320
#define WS_O2 576

// ---- K1 (cooperative, 64 blocks x 256): full head chain ----------------------
__global__ __launch_bounds__(256) void head_coop(
    const float* __restrict__ beta,
    const float* __restrict__ Wi, const float* __restrict__ bi,
    const float* __restrict__ Wn, const float* __restrict__ bn_b,
    const float* __restrict__ f1W, const float* __restrict__ f1b,
    const float* __restrict__ f2W, const float* __restrict__ f2b,
    const float* __restrict__ f3W, const float* __restrict__ f3b,
    float* __restrict__ ws)
{
    cg::grid_group grid = cg::this_grid();
    const int b    = blockIdx.x;    // 0..63
    const int t    = threadIdx.x;   // 0..255
    const int c0   = b * 4;
    const int lane = t & 63, wid = t >> 6;

    __shared__ float lds8[4][8];
    __shared__ float red[NOUT * 256];

    // ---------- phase 1: gate  h = (1-sigmoid(c@Wi+bi))*tanh(c@Wn+bn_b) ------
    {
        const float ck = beta[t];   // c[k]=beta[k mod 256]; fold rows k, k+256
        const float4 wi0 = *reinterpret_cast<const float4*>(&Wi[(size_t)t * HID + c0]);
        const float4 wi1 = *reinterpret_cast<const float4*>(&Wi[(size_t)(t + 256) * HID + c0]);
        const float4 wn0 = *reinterpret_cast<const float4*>(&Wn[(size_t)t * HID + c0]);
        const float4 wn1 = *reinterpret_cast<const float4*>(&Wn[(size_t)(t + 256) * HID + c0]);
        float v[8];
        v[0]=ck*(wi0.x+wi1.x); v[1]=ck*(wi0.y+wi1.y); v[2]=ck*(wi0.z+wi1.z); v[3]=ck*(wi0.w+wi1.w);
        v[4]=ck*(wn0.x+wn1.x); v[5]=ck*(wn0.y+wn1.y); v[6]=ck*(wn0.z+wn1.z); v[7]=ck*(wn0.w+wn1.w);
        #pragma unroll
        for (int off = 32; off; off >>= 1) {
            #pragma unroll
            for (int j = 0; j < 8; ++j) v[j] += __shfl_xor(v[j], off, 64);
        }
        if (lane == 0) {
            #pragma unroll
            for (int j = 0; j < 8; ++j) lds8[wid][j] = v[j];
        }
        __syncthreads();
        if (t < 4) {
            const float ai = lds8[0][t]+lds8[1][t]+lds8[2][t]+lds8[3][t];
            const float an = lds8[0][4+t]+lds8[1][4+t]+lds8[2][4+t]+lds8[3][4+t];
            const int c = c0 + t;
            const float iv = 1.f / (1.f + expf(-(ai + bi[c])));
            const float nv = tanhf(an + bn_b[c]);
            ws[WS_H + c] = (1.f - iv) * nv;   // hidden = (1-i)*n
        }
    }
    __threadfence();
    grid.sync();

    // ---------- phase 2: o1 = relu(h @ f1W + f1b) ----------------------------
    {
        const float hv = ws[WS_H + t];
        const float4 w = *reinterpret_cast<const float4*>(&f1W[(size_t)t * HID + c0]);
        float v[4] = {hv*w.x, hv*w.y, hv*w.z, hv*w.w};
        #pragma unroll
        for (int off = 32; off; off >>= 1) {
            #pragma unroll
            for (int j = 0; j < 4; ++j) v[j] += __shfl_xor(v[j], off, 64);
        }
        if (lane == 0) {
            #pragma unroll
            for (int j = 0; j < 4; ++j) lds8[wid][j] = v[j];
        }
        __syncthreads();
        if (t < 4) {
            const float a = lds8[0][t]+lds8[1][t]+lds8[2][t]+lds8[3][t];
            ws[WS_O1 + c0 + t] = fmaxf(a + f1b[c0 + t], 0.f);
        }
    }
    __threadfence();
    grid.sync();

    // ---------- phase 3: o2 = relu(o1 @ f2W + f2b) ---------------------------
    {
        const float hv = ws[WS_O1 + t];
        const float4 w = *reinterpret_cast<const float4*>(&f2W[(size_t)t * HID + c0]);
        float v[4] = {hv*w.x, hv*w.y, hv*w.z, hv*w.w};
        #pragma unroll
        for (int off = 32; off; off >>= 1) {
            #pragma unroll
            for (int j = 0; j < 4; ++j) v[j] += __shfl_xor(v[j], off, 64);
        }
        if (lane == 0) {
            #pragma unroll
            for (int j = 0; j < 4; ++j) lds8[wid][j] = v[j];
        }
        __syncthreads();
        if (t < 4) {
            const float a = lds8[0][t]+lds8[1][t]+lds8[2][t]+lds8[3][t];
            ws[WS_O2 + c0 + t] = fmaxf(a + f2b[c0 + t], 0.f);
        }
    }
    __threadfence();
    grid.sync();

    // ---------- phase 4: L = o2 @ f3W + f3b; prob = softmax(L) (block 0) -----
    if (b == 0) {
        const float o2 = ws[WS_O2 + t];
        const float4 wlo = *reinterpret_cast<const float4*>(&f3W[(size_t)t * NOUT]);
        const float4 whi = *reinterpret_cast<const float4*>(&f3W[(size_t)t * NOUT + 4]);
        red[0*256+t]=o2*wlo.x; red[1*256+t]=o2*wlo.y;
        red[2*256+t]=o2*wlo.z; red[3*256+t]=o2*wlo.w;
        red[4*256+t]=o2*whi.x; red[5*256+t]=o2*whi.y;
        red[6*256+t]=o2*whi.z; red[7*256+t]=o2*whi.w;
        __syncthreads();
        for (int s = 128; s; s >>= 1) {
            if (t < s) {
                #pragma unroll
                for (int j = 0; j < NOUT; ++j) red[j*256+t] += red[j*256+t+s];
            }
            __syncthreads();
        }
        if (t == 0) {
            float L[NOUT];
            #pragma unroll
            for (int j = 0; j < NOUT; ++j) L[j] = red[j*256] + f3b[j];
            float m = L[0];
            #pragma unroll
            for (int j = 1; j < NOUT; ++j) m = fmaxf(m, L[j]);
            float e[NOUT], s = 0.f;
            #pragma unroll
            for (int j = 0; j < NOUT; ++j) { e[j] = expf(L[j] - m); s += e[j]; }
            const float inv = 1.f / s;
            #pragma unroll
            for (int j = 0; j < NOUT; ++j) {
                ws[j] = L[j];
                ws[NOUT + j] = e[j] * inv;
            }
        }
    }
}

// ---- K2: per-row gumbel softmax + broadcast prob (no device-scope ops) -------
__global__ __launch_bounds__(256) void gumbel_kernel(
    const float* __restrict__ gn,  // [rows, 8] fp32
    const float* __restrict__ ws,  // L[8], prob[8]
    float* __restrict__ out,       // g_graph [rows,8] then prob [rows,8], fp32
    int rows)
{
    const int r = blockIdx.x * blockDim.x + threadIdx.x;
    if (r >= rows) return;

    float L[NOUT];
    #pragma unroll
    for (int j = 0; j < NOUT; ++j) L[j] = ws[j];

    const float4* gp = reinterpret_cast<const float4*>(gn + (size_t)r * NOUT);
    const float4 g0 = gp[0];
    const float4 g1 = gp[1];
    const float g[NOUT] = {g0.x, g0.y, g0.z, g0.w, g1.x, g1.y, g1.z, g1.w};

    float z[NOUT];
    float m = -1e30f;
    #pragma unroll
    for (int j = 0; j < NOUT; ++j) {
        z[j] = (L[j] + g[j]) * 2.0f;   // 1/TAU = 2
        m = fmaxf(m, z[j]);
    }
    float s = 0.f;
    #pragma unroll
    for (int j = 0; j < NOUT; ++j) { z[j] = expf(z[j] - m); s += z[j]; }
    const float inv = 1.f / s;

    float4* op = reinterpret_cast<float4*>(out + (size_t)r * NOUT);
    op[0] = make_float4(z[0]*inv, z[1]*inv, z[2]*inv, z[3]*inv);
    op[1] = make_float4(z[4]*inv, z[5]*inv, z[6]*inv, z[7]*inv);

    float4* pp = reinterpret_cast<float4*>(out + (size_t)(rows + r) * NOUT);
    pp[0] = make_float4(ws[8],  ws[9],  ws[10], ws[11]);
    pp[1] = make_float4(ws[12], ws[13], ws[14], ws[15]);
}

extern "C" void kernel_launch(void* const* d_in, const int* in_sizes, int n_in,
                              void* d_out, int out_size, void* d_ws, size_t ws_size,
                              hipStream_t stream) {
    // 0 graph, 1 rel_rec, 2 rel_send, 3 gumbel_noise,
    // 4 m1_W1, 5 m1_b1, 6 m1_W2, 7 m1_b2, 8 m1_g, 9 m1_beta,
    // 10 m2_W1, 11 m2_b1, 12 m2_W2, 13 m2_b2, 14 m2_g, 15 m2_beta,
    // 16 Wi, 17 bi, 18 Wn, 19 bn_b, 20 f1_W, 21 f1_b, 22 f2_W, 23 f2_b,
    // 24 f3_W, 25 f3_b
    const float* gumbel  = (const float*)d_in[3];
    const float* m2_beta = (const float*)d_in[15];
    const float* Wi      = (const float*)d_in[16];
    const float* bi      = (const float*)d_in[17];
    const float* Wn      = (const float*)d_in[18];
    const float* bn_b    = (const float*)d_in[19];
    const float* f1W     = (const float*)d_in[20];
    const float* f1b     = (const float*)d_in[21];
    const float* f2W     = (const float*)d_in[22];
    const float* f2b     = (const float*)d_in[23];
    const float* f3W     = (const float*)d_in[24];
    const float* f3b     = (const float*)d_in[25];

    const int rows = in_sizes[3] / NOUT;   // 260096
    float* ws = (float*)d_ws;

    void* args[] = {
        (void*)&m2_beta,
        (void*)&Wi, (void*)&bi, (void*)&Wn, (void*)&bn_b,
        (void*)&f1W, (void*)&f1b, (void*)&f2W, (void*)&f2b,
        (void*)&f3W, (void*)&f3b, (void*)&ws,
    };
    hipLaunchCooperativeKernel(reinterpret_cast<const void*>(head_coop),
                               dim3(64), dim3(256), args, 0, stream);

    const int threads = 256;
    const int blocks = (rows + threads - 1) / threads;
    gumbel_kernel<<<blocks, threads, 0, stream>>>(gumbel, ws, (float*)d_out, rows);
}

// Round 9
// 22.634 us; speedup vs baseline: 5.3318x; 3.3400x over previous
//
#include <hip/hip_runtime.h>

// B=16, N=128, F_IN=8, FC=256, H=256, E=N*(N-1)=16256, rows=B*E=260096, TAU=0.5
//
// Collapse (exact): graph is broadcast from graph[0,0] -> identical rows ->
// batchnorm over identical rows outputs exactly beta for both MLPs. Head input
// is one 512-vector [m2_beta, m2_beta] for ALL B*E rows: logits L[8] and
// prob=softmax(L) are computed ONCE; per-row work is only
// g_graph = softmax((L + gumbel)/TAU).
//
// Round-9: R7/R8 measured that in-kernel cross-block sync is catastrophic on
// gfx950 (agent-scope atomic storms: 150us; cooperative grid.sync: +50us).
// Keep R6's plain dependent-dispatch structure but fold f3+softmax INTO the
// gumbel kernel, computed redundantly per block from o2[256] + f3W (9KB,
// L2-resident) via shuffle reduction — deletes one node and one node gap.
// Chain: gate(64) -> f1(64) -> f2(64) -> gumbel_f3(1016). 4 nodes.

#define FC   256
#define HID  256
#define NOUT 8

// ws float offsets: [64..319]=h, [320..575]=o1, [576..831]=o2
#define WS_H  64
#define WS_O1 320
#define WS_O2 576

// ---- K1: gate layer, h = (1-sigmoid(c@Wi+bi)) * tanh(c@Wn+bn_b) -------------
// c[k] = beta[k mod 256] for k in [0,512); fold rows k and k+256.
__global__ __launch_bounds__(256) void gate_cols(
    const float* __restrict__ beta,
    const float* __restrict__ Wi, const float* __restrict__ Wn,
    const float* __restrict__ bi, const float* __restrict__ bn_b,
    float* __restrict__ ws)
{
    const int b  = blockIdx.x;     // 0..63
    const int t  = threadIdx.x;    // 0..255 (= k mod 256)
    const int c0 = b * 4;

    const float ck = beta[t];
    const float4 wi0 = *reinterpret_cast<const float4*>(&Wi[(size_t)t * HID + c0]);
    const float4 wi1 = *reinterpret_cast<const float4*>(&Wi[(size_t)(t + 256) * HID + c0]);
    const float4 wn0 = *reinterpret_cast<const float4*>(&Wn[(size_t)t * HID + c0]);
    const float4 wn1 = *reinterpret_cast<const float4*>(&Wn[(size_t)(t + 256) * HID + c0]);

    float v[8];
    v[0] = ck * (wi0.x + wi1.x); v[1] = ck * (wi0.y + wi1.y);
    v[2] = ck * (wi0.z + wi1.z); v[3] = ck * (wi0.w + wi1.w);
    v[4] = ck * (wn0.x + wn1.x); v[5] = ck * (wn0.y + wn1.y);
    v[6] = ck * (wn0.z + wn1.z); v[7] = ck * (wn0.w + wn1.w);

    #pragma unroll
    for (int off = 32; off > 0; off >>= 1) {
        #pragma unroll
        for (int j = 0; j < 8; ++j) v[j] += __shfl_xor(v[j], off, 64);
    }

    __shared__ float lds[4][8];
    const int lane = t & 63, wid = t >> 6;
    if (lane == 0) {
        #pragma unroll
        for (int j = 0; j < 8; ++j) lds[wid][j] = v[j];
    }
    __syncthreads();
    if (t < 4) {
        const float ai = lds[0][t] + lds[1][t] + lds[2][t] + lds[3][t];
        const float an = lds[0][4 + t] + lds[1][4 + t] + lds[2][4 + t] + lds[3][4 + t];
        const int c = c0 + t;
        const float iv = 1.f / (1.f + expf(-(ai + bi[c])));
        const float nv = tanhf(an + bn_b[c]);
        ws[WS_H + c] = (1.f - iv) * nv;   // hidden = (1-i)*n
    }
}

// ---- K2/K3: y[c0..c0+4) = relu(x @ W + bias), 64 blocks ----------------------
__global__ __launch_bounds__(256) void fc_cols(
    const float* __restrict__ W, const float* __restrict__ bias,
    const float* __restrict__ vin, float* __restrict__ vout)
{
    const int b  = blockIdx.x;     // 0..63
    const int t  = threadIdx.x;    // 0..255 (= k)
    const int c0 = b * 4;

    const float hv = vin[t];
    const float4 w = *reinterpret_cast<const float4*>(&W[(size_t)t * HID + c0]);
    float v[4] = {hv * w.x, hv * w.y, hv * w.z, hv * w.w};

    #pragma unroll
    for (int off = 32; off > 0; off >>= 1) {
        #pragma unroll
        for (int j = 0; j < 4; ++j) v[j] += __shfl_xor(v[j], off, 64);
    }

    __shared__ float lds[4][4];
    const int lane = t & 63, wid = t >> 6;
    if (lane == 0) {
        #pragma unroll
        for (int j = 0; j < 4; ++j) lds[wid][j] = v[j];
    }
    __syncthreads();
    if (t < 4) {
        const float a = lds[0][t] + lds[1][t] + lds[2][t] + lds[3][t];
        vout[c0 + t] = fmaxf(a + bias[c0 + t], 0.f);
    }
}

// ---- K4: per-row gumbel softmax; f3+softmax computed redundantly per block ---
__global__ __launch_bounds__(256) void gumbel_f3(
    const float* __restrict__ gn,   // [rows, 8] fp32
    const float* __restrict__ o2v,  // ws + WS_O2, 256 floats
    const float* __restrict__ f3W,  // [256][8]
    const float* __restrict__ f3b,  // [8]
    float* __restrict__ out,        // g_graph [rows,8] then prob [rows,8]
    int rows)
{
    const int t  = threadIdx.x;
    const int r0 = blockIdx.x * 256 + t;

    // ---- prefetch this thread's gumbel row (HBM latency hides under f3) -----
    float4 ga = make_float4(0.f, 0.f, 0.f, 0.f), gb = ga;
    if (r0 < rows) {
        const float4* gp = reinterpret_cast<const float4*>(gn + (size_t)r0 * NOUT);
        ga = gp[0]; gb = gp[1];
    }

    // ---- redundant f3: L = o2 @ f3W + f3b (9KB, L2-resident) ----------------
    const float o2 = o2v[t];
    const float4 wlo = *reinterpret_cast<const float4*>(&f3W[(size_t)t * NOUT]);
    const float4 whi = *reinterpret_cast<const float4*>(&f3W[(size_t)t * NOUT + 4]);
    float v[NOUT] = {o2*wlo.x, o2*wlo.y, o2*wlo.z, o2*wlo.w,
                     o2*whi.x, o2*whi.y, o2*whi.z, o2*whi.w};
    #pragma unroll
    for (int off = 32; off > 0; off >>= 1) {
        #pragma unroll
        for (int j = 0; j < NOUT; ++j) v[j] += __shfl_xor(v[j], off, 64);
    }

    __shared__ float part[4][NOUT];
    __shared__ float sLp[16];
    const int lane = t & 63, wid = t >> 6;
    if (lane == 0) {
        #pragma unroll
        for (int j = 0; j < NOUT; ++j) part[wid][j] = v[j];
    }
    __syncthreads();
    if (t == 0) {
        float L[NOUT];
        #pragma unroll
        for (int j = 0; j < NOUT; ++j)
            L[j] = part[0][j] + part[1][j] + part[2][j] + part[3][j] + f3b[j];
        float m = L[0];
        #pragma unroll
        for (int j = 1; j < NOUT; ++j) m = fmaxf(m, L[j]);
        float e[NOUT], s = 0.f;
        #pragma unroll
        for (int j = 0; j < NOUT; ++j) { e[j] = expf(L[j] - m); s += e[j]; }
        const float inv = 1.f / s;
        #pragma unroll
        for (int j = 0; j < NOUT; ++j) {
            sLp[j]     = 2.f * L[j];     // pre-scaled by 1/TAU = 2
            sLp[8 + j] = e[j] * inv;     // prob
        }
    }
    __syncthreads();

    if (r0 >= rows) return;

    float L2[NOUT];
    #pragma unroll
    for (int j = 0; j < NOUT; ++j) L2[j] = sLp[j];
    const float4 pr0 = make_float4(sLp[8],  sLp[9],  sLp[10], sLp[11]);
    const float4 pr1 = make_float4(sLp[12], sLp[13], sLp[14], sLp[15]);

    float z[NOUT] = {ga.x, ga.y, ga.z, ga.w, gb.x, gb.y, gb.z, gb.w};
    float m = -1e30f;
    #pragma unroll
    for (int j = 0; j < NOUT; ++j) { z[j] = L2[j] + 2.f * z[j]; m = fmaxf(m, z[j]); }
    float s = 0.f;
    #pragma unroll
    for (int j = 0; j < NOUT; ++j) { z[j] = expf(z[j] - m); s += z[j]; }
    const float inv = 1.f / s;

    float4* op = reinterpret_cast<float4*>(out + (size_t)r0 * NOUT);
    op[0] = make_float4(z[0]*inv, z[1]*inv, z[2]*inv, z[3]*inv);
    op[1] = make_float4(z[4]*inv, z[5]*inv, z[6]*inv, z[7]*inv);

    float4* pp = reinterpret_cast<float4*>(out + (size_t)(rows + r0) * NOUT);
    pp[0] = pr0; pp[1] = pr1;
}

extern "C" void kernel_launch(void* const* d_in, const int* in_sizes, int n_in,
                              void* d_out, int out_size, void* d_ws, size_t ws_size,
                              hipStream_t stream) {
    // 0 graph, 1 rel_rec, 2 rel_send, 3 gumbel_noise,
    // 4 m1_W1, 5 m1_b1, 6 m1_W2, 7 m1_b2, 8 m1_g, 9 m1_beta,
    // 10 m2_W1, 11 m2_b1, 12 m2_W2, 13 m2_b2, 14 m2_g, 15 m2_beta,
    // 16 Wi, 17 bi, 18 Wn, 19 bn_b, 20 f1_W, 21 f1_b, 22 f2_W, 23 f2_b,
    // 24 f3_W, 25 f3_b
    const float* gumbel  = (const float*)d_in[3];
    const float* m2_beta = (const float*)d_in[15];
    const float* Wi      = (const float*)d_in[16];
    const float* bi      = (const float*)d_in[17];
    const float* Wn      = (const float*)d_in[18];
    const float* bn_b    = (const float*)d_in[19];
    const float* f1W     = (const float*)d_in[20];
    const float* f1b     = (const float*)d_in[21];
    const float* f2W     = (const float*)d_in[22];
    const float* f2b     = (const float*)d_in[23];
    const float* f3W     = (const float*)d_in[24];
    const float* f3b     = (const float*)d_in[25];

    const int rows = in_sizes[3] / NOUT;   // 260096
    float* ws = (float*)d_ws;

    gate_cols<<<64, 256, 0, stream>>>(m2_beta, Wi, Wn, bi, bn_b, ws);
    fc_cols<<<64, 256, 0, stream>>>(f1W, f1b, ws + WS_H,  ws + WS_O1);
    fc_cols<<<64, 256, 0, stream>>>(f2W, f2b, ws + WS_O1, ws + WS_O2);

    const int blocks = (rows + 255) / 256;   // 1016
    gumbel_f3<<<blocks, 256, 0, stream>>>(gumbel, ws + WS_O2, f3W, f3b,
                                          (float*)d_out, rows);
}

// Round 10
// 22.364 us; speedup vs baseline: 5.3962x; 1.0121x over previous
//
#include <hip/hip_runtime.h>

// B=16, N=128, F_IN=8, FC=256, H=256, E=N*(N-1)=16256, rows=B*E=260096, TAU=0.5
//
// Collapse (exact): graph is broadcast from graph[0,0] -> identical rows ->
// batchnorm over identical rows outputs exactly beta for both MLPs. Head input
// is one 512-vector [m2_beta, m2_beta] for ALL B*E rows: logits L[8] and
// prob=softmax(L) are computed ONCE; per-row work is only
// g_graph = softmax((L + gumbel)/TAU).
//
// Round-10: launch-overhead-bound (kernels ~5.5us of 22.6us; ~1us/node).
// Node floor = one dispatch per {nonlinearity after a block-distributed
// matvec} = 2 (h->o1, o1->o2) + the streaming kernel. f3 is LINEAR -> defer
// as per-block partials reduced inside the gumbel kernel.
//   K1 gate+f1-partials(64) -> K2 f1-reduce+f2+f3-partials(64)
//   -> K3 gumbel+p3-reduce(1016).  3 nodes.
// R7/R8 measured: in-kernel cross-block sync (agent-scope flags / coop
// grid.sync) is catastrophic on gfx950 -- plain dependent dispatches only.

#define FC   256
#define HID  256
#define NOUT 8

// ws float offsets
#define WS_P3 512                 // [64][8]  f3 partials
#define WS_P1 1024                // [64][256] f1 partials

// ---- K1: gate cols + f1 partials ---------------------------------------------
// block b owns h columns c0..c0+3. c[k]=beta[k mod 256], fold rows k,k+256.
__global__ __launch_bounds__(256) void gate_f1p(
    const float* __restrict__ beta,
    const float* __restrict__ Wi, const float* __restrict__ Wn,
    const float* __restrict__ bi, const float* __restrict__ bn_b,
    const float* __restrict__ f1W,
    float* __restrict__ ws)
{
    const int b  = blockIdx.x;     // 0..63
    const int t  = threadIdx.x;    // 0..255 (= k mod 256)
    const int c0 = b * 4;

    const float ck = beta[t];
    const float4 wi0 = *reinterpret_cast<const float4*>(&Wi[(size_t)t * HID + c0]);
    const float4 wi1 = *reinterpret_cast<const float4*>(&Wi[(size_t)(t + 256) * HID + c0]);
    const float4 wn0 = *reinterpret_cast<const float4*>(&Wn[(size_t)t * HID + c0]);
    const float4 wn1 = *reinterpret_cast<const float4*>(&Wn[(size_t)(t + 256) * HID + c0]);

    float v[8];
    v[0] = ck * (wi0.x + wi1.x); v[1] = ck * (wi0.y + wi1.y);
    v[2] = ck * (wi0.z + wi1.z); v[3] = ck * (wi0.w + wi1.w);
    v[4] = ck * (wn0.x + wn1.x); v[5] = ck * (wn0.y + wn1.y);
    v[6] = ck * (wn0.z + wn1.z); v[7] = ck * (wn0.w + wn1.w);

    #pragma unroll
    for (int off = 32; off > 0; off >>= 1) {
        #pragma unroll
        for (int j = 0; j < 8; ++j) v[j] += __shfl_xor(v[j], off, 64);
    }

    __shared__ float lds[4][8];
    __shared__ float hv4[4];
    const int lane = t & 63, wid = t >> 6;
    if (lane == 0) {
        #pragma unroll
        for (int j = 0; j < 8; ++j) lds[wid][j] = v[j];
    }
    __syncthreads();
    if (t < 4) {
        const float ai = lds[0][t] + lds[1][t] + lds[2][t] + lds[3][t];
        const float an = lds[0][4 + t] + lds[1][4 + t] + lds[2][4 + t] + lds[3][4 + t];
        const int c = c0 + t;
        const float iv = 1.f / (1.f + __expf(-(ai + bi[c])));
        const float nv = tanhf(an + bn_b[c]);
        hv4[t] = (1.f - iv) * nv;          // h[c] = (1-i)*n
    }
    __syncthreads();

    // f1 partials: p1[b][t] = sum_{i<4} h[c0+i] * f1W[c0+i][t]
    const float p = hv4[0] * f1W[(size_t)(c0 + 0) * HID + t]
                  + hv4[1] * f1W[(size_t)(c0 + 1) * HID + t]
                  + hv4[2] * f1W[(size_t)(c0 + 2) * HID + t]
                  + hv4[3] * f1W[(size_t)(c0 + 3) * HID + t];
    ws[WS_P1 + b * 256 + t] = p;
}

// ---- K2: reduce p1 -> o1; f2 cols -> o2[c0..c0+4); f3 partials ---------------
__global__ __launch_bounds__(256) void f1r_f2_f3p(
    const float* __restrict__ f1b,
    const float* __restrict__ f2W, const float* __restrict__ f2b,
    const float* __restrict__ f3W,
    float* __restrict__ ws)
{
    const int b  = blockIdx.x;     // 0..63
    const int t  = threadIdx.x;    // 0..255
    const int c0 = b * 4;

    // o1[t] = relu(sum_b p1[b][t] + f1b[t])
    float a = 0.f;
    #pragma unroll 8
    for (int k = 0; k < 64; ++k) a += ws[WS_P1 + k * 256 + t];
    const float o1 = fmaxf(a + f1b[t], 0.f);

    // f2 columns c0..c0+3
    const float4 w = *reinterpret_cast<const float4*>(&f2W[(size_t)t * HID + c0]);
    float v[4] = {o1 * w.x, o1 * w.y, o1 * w.z, o1 * w.w};
    #pragma unroll
    for (int off = 32; off > 0; off >>= 1) {
        #pragma unroll
        for (int j = 0; j < 4; ++j) v[j] += __shfl_xor(v[j], off, 64);
    }

    __shared__ float lds[4][4];
    __shared__ float o2s[4];
    const int lane = t & 63, wid = t >> 6;
    if (lane == 0) {
        #pragma unroll
        for (int j = 0; j < 4; ++j) lds[wid][j] = v[j];
    }
    __syncthreads();
    if (t < 4) {
        const float s = lds[0][t] + lds[1][t] + lds[2][t] + lds[3][t];
        o2s[t] = fmaxf(s + f2b[c0 + t], 0.f);
    }
    __syncthreads();

    // f3 partials: p3[b][j] = sum_{i<4} o2[c0+i] * f3W[c0+i][j]
    if (t < NOUT) {
        const float p = o2s[0] * f3W[(size_t)(c0 + 0) * NOUT + t]
                      + o2s[1] * f3W[(size_t)(c0 + 1) * NOUT + t]
                      + o2s[2] * f3W[(size_t)(c0 + 2) * NOUT + t]
                      + o2s[3] * f3W[(size_t)(c0 + 3) * NOUT + t];
        ws[WS_P3 + b * NOUT + t] = p;
    }
}

// ---- K3: reduce p3 -> L, softmax; per-row gumbel softmax ----------------------
__global__ __launch_bounds__(256) void gumbel_red(
    const float* __restrict__ gn,   // [rows, 8] fp32
    const float* __restrict__ ws,   // p3 at WS_P3
    const float* __restrict__ f3b,  // [8]
    float* __restrict__ out,        // g_graph [rows,8] then prob [rows,8]
    int rows)
{
    const int t  = threadIdx.x;
    const int r0 = blockIdx.x * 256 + t;

    // prefetch this thread's gumbel row (HBM latency hides under the preamble)
    float4 ga = make_float4(0.f, 0.f, 0.f, 0.f), gb = ga;
    if (r0 < rows) {
        const float4* gp = reinterpret_cast<const float4*>(gn + (size_t)r0 * NOUT);
        ga = gp[0]; gb = gp[1];
    }

    __shared__ float sLp[16];
    if (t < 64) {   // wave 0 only
        const float4 pa = *reinterpret_cast<const float4*>(&ws[WS_P3 + t * NOUT]);
        const float4 pb = *reinterpret_cast<const float4*>(&ws[WS_P3 + t * NOUT + 4]);
        float v[NOUT] = {pa.x, pa.y, pa.z, pa.w, pb.x, pb.y, pb.z, pb.w};
        #pragma unroll
        for (int off = 32; off > 0; off >>= 1) {
            #pragma unroll
            for (int j = 0; j < NOUT; ++j) v[j] += __shfl_xor(v[j], off, 64);
        }
        if (t == 0) {
            float L[NOUT];
            #pragma unroll
            for (int j = 0; j < NOUT; ++j) L[j] = v[j] + f3b[j];
            float m = L[0];
            #pragma unroll
            for (int j = 1; j < NOUT; ++j) m = fmaxf(m, L[j]);
            float e[NOUT], s = 0.f;
            #pragma unroll
            for (int j = 0; j < NOUT; ++j) { e[j] = __expf(L[j] - m); s += e[j]; }
            const float inv = 1.f / s;
            #pragma unroll
            for (int j = 0; j < NOUT; ++j) {
                sLp[j]     = 2.f * L[j];     // pre-scaled by 1/TAU = 2
                sLp[8 + j] = e[j] * inv;     // prob
            }
        }
    }
    __syncthreads();

    if (r0 >= rows) return;

    float L2[NOUT];
    #pragma unroll
    for (int j = 0; j < NOUT; ++j) L2[j] = sLp[j];
    const float4 pr0 = make_float4(sLp[8],  sLp[9],  sLp[10], sLp[11]);
    const float4 pr1 = make_float4(sLp[12], sLp[13], sLp[14], sLp[15]);

    float z[NOUT] = {ga.x, ga.y, ga.z, ga.w, gb.x, gb.y, gb.z, gb.w};
    float m = -1e30f;
    #pragma unroll
    for (int j = 0; j < NOUT; ++j) { z[j] = L2[j] + 2.f * z[j]; m = fmaxf(m, z[j]); }
    float s = 0.f;
    #pragma unroll
    for (int j = 0; j < NOUT; ++j) { z[j] = __expf(z[j] - m); s += z[j]; }
    const float inv = 1.f / s;

    float4* op = reinterpret_cast<float4*>(out + (size_t)r0 * NOUT);
    op[0] = make_float4(z[0]*inv, z[1]*inv, z[2]*inv, z[3]*inv);
    op[1] = make_float4(z[4]*inv, z[5]*inv, z[6]*inv, z[7]*inv);

    float4* pp = reinterpret_cast<float4*>(out + (size_t)(rows + r0) * NOUT);
    pp[0] = pr0; pp[1] = pr1;
}

extern "C" void kernel_launch(void* const* d_in, const int* in_sizes, int n_in,
                              void* d_out, int out_size, void* d_ws, size_t ws_size,
                              hipStream_t stream) {
    // 0 graph, 1 rel_rec, 2 rel_send, 3 gumbel_noise,
    // 4 m1_W1, 5 m1_b1, 6 m1_W2, 7 m1_b2, 8 m1_g, 9 m1_beta,
    // 10 m2_W1, 11 m2_b1, 12 m2_W2, 13 m2_b2, 14 m2_g, 15 m2_beta,
    // 16 Wi, 17 bi, 18 Wn, 19 bn_b, 20 f1_W, 21 f1_b, 22 f2_W, 23 f2_b,
    // 24 f3_W, 25 f3_b
    const float* gumbel  = (const float*)d_in[3];
    const float* m2_beta = (const float*)d_in[15];
    const float* Wi      = (const float*)d_in[16];
    const float* bi      = (const float*)d_in[17];
    const float* Wn      = (const float*)d_in[18];
    const float* bn_b    = (const float*)d_in[19];
    const float* f1W     = (const float*)d_in[20];
    const float* f1b     = (const float*)d_in[21];
    const float* f2W     = (const float*)d_in[22];
    const float* f2b     = (const float*)d_in[23];
    const float* f3W     = (const float*)d_in[24];
    const float* f3b     = (const float*)d_in[25];

    const int rows = in_sizes[3] / NOUT;   // 260096
    float* ws = (float*)d_ws;

    gate_f1p<<<64, 256, 0, stream>>>(m2_beta, Wi, Wn, bi, bn_b, f1W, ws);
    f1r_f2_f3p<<<64, 256, 0, stream>>>(f1b, f2W, f2b, f3W, ws);

    const int blocks = (rows + 255) / 256;   // 1016
    gumbel_red<<<blocks, 256, 0, stream>>>(gumbel, ws, f3b, (float*)d_out, rows);
}

// Round 12
// 21.418 us; speedup vs baseline: 5.6345x; 1.0442x over previous
//
#include <hip/hip_runtime.h>

// B=16, N=128, F_IN=8, FC=256, H=256, E=N*(N-1)=16256, rows=B*E=260096, TAU=0.5
//
// Collapse (exact): graph is broadcast from graph[0,0] -> identical rows ->
// batchnorm over identical rows outputs exactly beta for both MLPs. Head input
// is one 512-vector [m2_beta, m2_beta] for ALL B*E rows: logits L[8] and
// prob=softmax(L) are computed ONCE; per-row work is only
// g_graph = softmax((L + gumbel)/TAU).
//
// Round-12: same as R11 (2 rows/thread, 508 blocks, nontemporal output
// stores) but with the compile fix: __builtin_nontemporal_store needs a
// NATIVE vector type, not HIP_vector_type<float,4> -- use ext_vector_type.
// R7/R8 measured: in-kernel cross-block sync is catastrophic on gfx950.

#define FC   256
#define HID  256
#define NOUT 8

typedef float f4 __attribute__((ext_vector_type(4)));

// ws float offsets
#define WS_P3 512                 // [64][8]  f3 partials
#define WS_P1 1024                // [64][256] f1 partials

// ---- K1: gate cols + f1 partials ---------------------------------------------
__global__ __launch_bounds__(256) void gate_f1p(
    const float* __restrict__ beta,
    const float* __restrict__ Wi, const float* __restrict__ Wn,
    const float* __restrict__ bi, const float* __restrict__ bn_b,
    const float* __restrict__ f1W,
    float* __restrict__ ws)
{
    const int b  = blockIdx.x;     // 0..63
    const int t  = threadIdx.x;    // 0..255 (= k mod 256)
    const int c0 = b * 4;

    const float ck = beta[t];
    const float4 wi0 = *reinterpret_cast<const float4*>(&Wi[(size_t)t * HID + c0]);
    const float4 wi1 = *reinterpret_cast<const float4*>(&Wi[(size_t)(t + 256) * HID + c0]);
    const float4 wn0 = *reinterpret_cast<const float4*>(&Wn[(size_t)t * HID + c0]);
    const float4 wn1 = *reinterpret_cast<const float4*>(&Wn[(size_t)(t + 256) * HID + c0]);

    float v[8];
    v[0] = ck * (wi0.x + wi1.x); v[1] = ck * (wi0.y + wi1.y);
    v[2] = ck * (wi0.z + wi1.z); v[3] = ck * (wi0.w + wi1.w);
    v[4] = ck * (wn0.x + wn1.x); v[5] = ck * (wn0.y + wn1.y);
    v[6] = ck * (wn0.z + wn1.z); v[7] = ck * (wn0.w + wn1.w);

    #pragma unroll
    for (int off = 32; off > 0; off >>= 1) {
        #pragma unroll
        for (int j = 0; j < 8; ++j) v[j] += __shfl_xor(v[j], off, 64);
    }

    __shared__ float lds[4][8];
    __shared__ float hv4[4];
    const int lane = t & 63, wid = t >> 6;
    if (lane == 0) {
        #pragma unroll
        for (int j = 0; j < 8; ++j) lds[wid][j] = v[j];
    }
    __syncthreads();
    if (t < 4) {
        const float ai = lds[0][t] + lds[1][t] + lds[2][t] + lds[3][t];
        const float an = lds[0][4 + t] + lds[1][4 + t] + lds[2][4 + t] + lds[3][4 + t];
        const int c = c0 + t;
        const float iv = 1.f / (1.f + __expf(-(ai + bi[c])));
        const float nv = tanhf(an + bn_b[c]);
        hv4[t] = (1.f - iv) * nv;          // h[c] = (1-i)*n
    }
    __syncthreads();

    // f1 partials: p1[b][t] = sum_{i<4} h[c0+i] * f1W[c0+i][t]
    const float p = hv4[0] * f1W[(size_t)(c0 + 0) * HID + t]
                  + hv4[1] * f1W[(size_t)(c0 + 1) * HID + t]
                  + hv4[2] * f1W[(size_t)(c0 + 2) * HID + t]
                  + hv4[3] * f1W[(size_t)(c0 + 3) * HID + t];
    ws[WS_P1 + b * 256 + t] = p;
}

// ---- K2: reduce p1 -> o1; f2 cols -> o2[c0..c0+4); f3 partials ---------------
__global__ __launch_bounds__(256) void f1r_f2_f3p(
    const float* __restrict__ f1b,
    const float* __restrict__ f2W, const float* __restrict__ f2b,
    const float* __restrict__ f3W,
    float* __restrict__ ws)
{
    const int b  = blockIdx.x;     // 0..63
    const int t  = threadIdx.x;    // 0..255
    const int c0 = b * 4;

    // o1[t] = relu(sum_b p1[b][t] + f1b[t])
    float a = 0.f;
    #pragma unroll 8
    for (int k = 0; k < 64; ++k) a += ws[WS_P1 + k * 256 + t];
    const float o1 = fmaxf(a + f1b[t], 0.f);

    // f2 columns c0..c0+3
    const float4 w = *reinterpret_cast<const float4*>(&f2W[(size_t)t * HID + c0]);
    float v[4] = {o1 * w.x, o1 * w.y, o1 * w.z, o1 * w.w};
    #pragma unroll
    for (int off = 32; off > 0; off >>= 1) {
        #pragma unroll
        for (int j = 0; j < 4; ++j) v[j] += __shfl_xor(v[j], off, 64);
    }

    __shared__ float lds[4][4];
    __shared__ float o2s[4];
    const int lane = t & 63, wid = t >> 6;
    if (lane == 0) {
        #pragma unroll
        for (int j = 0; j < 4; ++j) lds[wid][j] = v[j];
    }
    __syncthreads();
    if (t < 4) {
        const float s = lds[0][t] + lds[1][t] + lds[2][t] + lds[3][t];
        o2s[t] = fmaxf(s + f2b[c0 + t], 0.f);
    }
    __syncthreads();

    // f3 partials: p3[b][j] = sum_{i<4} o2[c0+i] * f3W[c0+i][j]
    if (t < NOUT) {
        const float p = o2s[0] * f3W[(size_t)(c0 + 0) * NOUT + t]
                      + o2s[1] * f3W[(size_t)(c0 + 1) * NOUT + t]
                      + o2s[2] * f3W[(size_t)(c0 + 2) * NOUT + t]
                      + o2s[3] * f3W[(size_t)(c0 + 3) * NOUT + t];
        ws[WS_P3 + b * NOUT + t] = p;
    }
}

// ---- K3: reduce p3 -> L, softmax; per-row gumbel, 2 rows/thread ---------------
__global__ __launch_bounds__(256) void gumbel_red(
    const float* __restrict__ gn,   // [rows, 8] fp32
    const float* __restrict__ ws,   // p3 at WS_P3
    const float* __restrict__ f3b,  // [8]
    float* __restrict__ out,        // g_graph [rows,8] then prob [rows,8]
    int rows)
{
    const int t  = threadIdx.x;
    const int rA = blockIdx.x * 512 + t;         // row 1
    const int rB = rA + 256;                     // row 2

    // issue both rows' gumbel loads first (hide HBM latency under preamble)
    float4 ga = make_float4(0.f,0.f,0.f,0.f), gb = ga, gc = ga, gd = ga;
    if (rA < rows) {
        const float4* gp = reinterpret_cast<const float4*>(gn + (size_t)rA * NOUT);
        ga = gp[0]; gb = gp[1];
    }
    if (rB < rows) {
        const float4* gp = reinterpret_cast<const float4*>(gn + (size_t)rB * NOUT);
        gc = gp[0]; gd = gp[1];
    }

    // preamble: reduce p3 -> L, softmax (wave 0 only)
    __shared__ float sLp[16];
    if (t < 64) {
        const float4 pa = *reinterpret_cast<const float4*>(&ws[WS_P3 + t * NOUT]);
        const float4 pb = *reinterpret_cast<const float4*>(&ws[WS_P3 + t * NOUT + 4]);
        float v[NOUT] = {pa.x, pa.y, pa.z, pa.w, pb.x, pb.y, pb.z, pb.w};
        #pragma unroll
        for (int off = 32; off > 0; off >>= 1) {
            #pragma unroll
            for (int j = 0; j < NOUT; ++j) v[j] += __shfl_xor(v[j], off, 64);
        }
        if (t == 0) {
            float L[NOUT];
            #pragma unroll
            for (int j = 0; j < NOUT; ++j) L[j] = v[j] + f3b[j];
            float m = L[0];
            #pragma unroll
            for (int j = 1; j < NOUT; ++j) m = fmaxf(m, L[j]);
            float e[NOUT], s = 0.f;
            #pragma unroll
            for (int j = 0; j < NOUT; ++j) { e[j] = __expf(L[j] - m); s += e[j]; }
            const float inv = 1.f / s;
            #pragma unroll
            for (int j = 0; j < NOUT; ++j) {
                sLp[j]     = 2.f * L[j];     // pre-scaled by 1/TAU = 2
                sLp[8 + j] = e[j] * inv;     // prob
            }
        }
    }
    __syncthreads();

    float L2[NOUT];
    #pragma unroll
    for (int j = 0; j < NOUT; ++j) L2[j] = sLp[j];
    const f4 pr0 = {sLp[8],  sLp[9],  sLp[10], sLp[11]};
    const f4 pr1 = {sLp[12], sLp[13], sLp[14], sLp[15]};

    // ---- row A ----
    if (rA < rows) {
        float z[NOUT] = {ga.x, ga.y, ga.z, ga.w, gb.x, gb.y, gb.z, gb.w};
        float m = -1e30f;
        #pragma unroll
        for (int j = 0; j < NOUT; ++j) { z[j] = L2[j] + 2.f * z[j]; m = fmaxf(m, z[j]); }
        float s = 0.f;
        #pragma unroll
        for (int j = 0; j < NOUT; ++j) { z[j] = __expf(z[j] - m); s += z[j]; }
        const float inv = 1.f / s;
        f4* op = reinterpret_cast<f4*>(out + (size_t)rA * NOUT);
        f4 z0 = {z[0]*inv, z[1]*inv, z[2]*inv, z[3]*inv};
        f4 z1 = {z[4]*inv, z[5]*inv, z[6]*inv, z[7]*inv};
        __builtin_nontemporal_store(z0, op);
        __builtin_nontemporal_store(z1, op + 1);
        f4* pp = reinterpret_cast<f4*>(out + (size_t)(rows + rA) * NOUT);
        __builtin_nontemporal_store(pr0, pp);
        __builtin_nontemporal_store(pr1, pp + 1);
    }
    // ---- row B ----
    if (rB < rows) {
        float z[NOUT] = {gc.x, gc.y, gc.z, gc.w, gd.x, gd.y, gd.z, gd.w};
        float m = -1e30f;
        #pragma unroll
        for (int j = 0; j < NOUT; ++j) { z[j] = L2[j] + 2.f * z[j]; m = fmaxf(m, z[j]); }
        float s = 0.f;
        #pragma unroll
        for (int j = 0; j < NOUT; ++j) { z[j] = __expf(z[j] - m); s += z[j]; }
        const float inv = 1.f / s;
        f4* op = reinterpret_cast<f4*>(out + (size_t)rB * NOUT);
        f4 z0 = {z[0]*inv, z[1]*inv, z[2]*inv, z[3]*inv};
        f4 z1 = {z[4]*inv, z[5]*inv, z[6]*inv, z[7]*inv};
        __builtin_nontemporal_store(z0, op);
        __builtin_nontemporal_store(z1, op + 1);
        f4* pp = reinterpret_cast<f4*>(out + (size_t)(rows + rB) * NOUT);
        __builtin_nontemporal_store(pr0, pp);
        __builtin_nontemporal_store(pr1, pp + 1);
    }
}

extern "C" void kernel_launch(void* const* d_in, const int* in_sizes, int n_in,
                              void* d_out, int out_size, void* d_ws, size_t ws_size,
                              hipStream_t stream) {
    // 0 graph, 1 rel_rec, 2 rel_send, 3 gumbel_noise,
    // 4 m1_W1, 5 m1_b1, 6 m1_W2, 7 m1_b2, 8 m1_g, 9 m1_beta,
    // 10 m2_W1, 11 m2_b1, 12 m2_W2, 13 m2_b2, 14 m2_g, 15 m2_beta,
    // 16 Wi, 17 bi, 18 Wn, 19 bn_b, 20 f1_W, 21 f1_b, 22 f2_W, 23 f2_b,
    // 24 f3_W, 25 f3_b
    const float* gumbel  = (const float*)d_in[3];
    const float* m2_beta = (const float*)d_in[15];
    const float* Wi      = (const float*)d_in[16];
    const float* bi      = (const float*)d_in[17];
    const float* Wn      = (const float*)d_in[18];
    const float* bn_b    = (const float*)d_in[19];
    const float* f1W     = (const float*)d_in[20];
    const float* f1b     = (const float*)d_in[21];
    const float* f2W     = (const float*)d_in[22];
    const float* f2b     = (const float*)d_in[23];
    const float* f3W     = (const float*)d_in[24];
    const float* f3b     = (const float*)d_in[25];

    const int rows = in_sizes[3] / NOUT;   // 260096
    float* ws = (float*)d_ws;

    gate_f1p<<<64, 256, 0, stream>>>(m2_beta, Wi, Wn, bi, bn_b, f1W, ws);
    f1r_f2_f3p<<<64, 256, 0, stream>>>(f1b, f2W, f2b, f3W, ws);

    const int blocks = (rows + 511) / 512;   // 508
    gumbel_red<<<blocks, 256, 0, stream>>>(gumbel, ws, f3b, (float*)d_out, rows);
}